// Round 9
// baseline (107.285 us; speedup 1.0000x reference)
//
#include <hip/hip_runtime.h>
#include <hip/hip_bf16.h>

#define NODES 1024
#define DIM   64
#define MINV  1e-15f
#define EPSV  1e-7f
#define HPAD  66
#define CH    64
#define GRID  1024

// matches reference: clip to [-1+1e-7, 1-1e-7], 0.5*(log1p(y)-log1p(-y))
__device__ __forceinline__ float artanh_f(float y) {
    y = fminf(fmaxf(y, -1.f + EPSV), 1.f - EPSV);
    return 0.5f * (log1pf(y) - log1pf(-y));
}

__device__ __forceinline__ float waveReduceSum(float v) {
#pragma unroll
    for (int m = 1; m < 64; m <<= 1) v += __shfl_xor(v, m, 64);
    return v;
}
// independent reductions, interleaved shuffles: same per-sum order, half latency
__device__ __forceinline__ void waveReduceSum2(float& a, float& b) {
#pragma unroll
    for (int m = 1; m < 64; m <<= 1) {
        const float ta = __shfl_xor(a, m, 64);
        const float tb = __shfl_xor(b, m, 64);
        a += ta; b += tb;
    }
}
__device__ __forceinline__ void waveReduceSum3(float& a, float& b, float& c) {
#pragma unroll
    for (int m = 1; m < 64; m <<= 1) {
        const float ta = __shfl_xor(a, m, 64);
        const float tb = __shfl_xor(b, m, 64);
        const float tc = __shfl_xor(c, m, 64);
        a += ta; b += tb; c += tc;
    }
}

// ---- fused, one node per block: prep -> compaction -> grid barrier -> agg ----
__global__ __launch_bounds__(256, 4) void fused_kernel(
    const float* __restrict__ x,
    const float* __restrict__ adj,
    const float* __restrict__ weight,
    const float* __restrict__ bias,
    const float* __restrict__ att_w,
    const float* __restrict__ att_b,
    float* __restrict__ H, float* __restrict__ X2,
    float* __restrict__ L, float* __restrict__ R,
    unsigned* __restrict__ bar,
    float* __restrict__ out)
{
    __shared__ float sx[DIM];
    __shared__ float smx[DIM];
    __shared__ float shi[DIM];
    __shared__ float Hl[CH][HPAD];
    __shared__ float f_arr[CH];
    __shared__ int   slist[NODES];
    __shared__ int   wbase[4];
    __shared__ float svred[4][DIM];
    __shared__ float s0red[4];

    const int i   = blockIdx.x;
    const int tid = threadIdx.x;
    const int wv  = tid >> 6;
    const int ln  = tid & 63;

    // ================= Part A: prep node i (all 256 threads) =================
    if (tid < DIM) sx[tid] = x[i * DIM + tid];
    __syncthreads();

    // mx[t] = sum_d x[d]*W[t][d] : 4 lanes per t, coalesced W reads (lines reused across k)
    {
        const int tdim = tid >> 2;       // 0..63
        const int seg  = tid & 3;        // 0..3
        float part = 0.f;
        const float* wrow = weight + tdim * DIM + seg * 16;
        const float* sxs  = sx + seg * 16;
#pragma unroll
        for (int k = 0; k < 16; k += 4) {
            const float4 w4 = *reinterpret_cast<const float4*>(wrow + k);
            part = fmaf(sxs[k + 0], w4.x, part);
            part = fmaf(sxs[k + 1], w4.y, part);
            part = fmaf(sxs[k + 2], w4.z, part);
            part = fmaf(sxs[k + 3], w4.w, part);
        }
        part += __shfl_xor(part, 1, 64);
        part += __shfl_xor(part, 2, 64);
        if (seg == 0) smx[tdim] = part;
    }
    __syncthreads();

    // all 4 waves redundantly run the in-wave scalar chain (no cross-wave reductions)
    const float xd  = sx[ln];
    const float mxv = smx[ln];
    const float bd  = bias[ln];
    float xn2 = xd * xd, mxn2 = mxv * mxv, bn2 = bd * bd;
    waveReduceSum3(xn2, mxn2, bn2);
    const float xn  = fmaxf(sqrtf(xn2), MINV);
    const float mxn = fmaxf(sqrtf(mxn2), MINV);
    const float res = tanhf(mxn / xn * artanh_f(xn)) * mxv / mxn;   // mobius_matvec (c=1)
    const float bn  = fmaxf(sqrtf(bn2), MINV);
    const float hb  = tanhf(bn) * bd / bn;                          // expmap0(bias)

    float y2b = hb * hb, x2r = res * res, xyb = res * hb;
    waveReduceSum3(y2b, x2r, xyb);
    const float numA = (1.f + 2.f * xyb + y2b) * res + (1.f - x2r) * hb;
    const float denA = fmaxf(1.f + 2.f * xyb + x2r * y2b, MINV);
    const float h    = numA / denA;                                 // mobius_add -> h

    const float x2i = waveReduceSum(h * h);
    const float n   = fmaxf(sqrtf(x2i), MINV);
    const float ht  = artanh_f(n) / n * h;                          // logmap0
    float Li = ht * att_w[ln], Ri = ht * att_w[DIM + ln];
    waveReduceSum2(Li, Ri);

    if (wv == 0) { H[i * DIM + ln] = h; shi[ln] = h; }
    if (tid == 0) { X2[i] = x2i; L[i] = Li; R[i] = Ri; }

    // ================= compaction of adj row (independent of Part A results) =================
    const float4 a4 = *reinterpret_cast<const float4*>(adj + i * NODES + tid * 4);
    const int c0 = (a4.x != 0.f), c1 = (a4.y != 0.f), c2 = (a4.z != 0.f), c3 = (a4.w != 0.f);
    const int cntv = c0 + c1 + c2 + c3;

    int pfx = cntv;
#pragma unroll
    for (int d = 1; d < 64; d <<= 1) {
        const int tsh = __shfl_up(pfx, d, 64);
        if (ln >= d) pfx += tsh;
    }
    if (ln == 63) wbase[wv] = pfx;
    __syncthreads();

    int base = 0;
#pragma unroll
    for (int w = 0; w < 4; ++w) if (w < wv) base += wbase[w];
    int pos = base + pfx - cntv;
    const int j0 = tid * 4;
    if (c0) slist[pos++] = j0 + 0;
    if (c1) slist[pos++] = j0 + 1;
    if (c2) slist[pos++] = j0 + 2;
    if (c3) slist[pos++] = j0 + 3;
    const int cnt0 = wbase[0], cnt1 = wbase[1], cnt2 = wbase[2], cnt3 = wbase[3];
    const int cnt = cnt0 + cnt1 + cnt2 + cnt3;

    // ================= grid barrier (device-scope, XCD-safe; R8-proven) =================
    __syncthreads();
    if (tid == 0) {
        __threadfence();                         // release
        atomicAdd(bar, 1u);
        unsigned spins = 0;
        while (atomicAdd(bar, 0u) < GRID && ++spins < 100000000u)
            __builtin_amdgcn_s_sleep(2);
        __threadfence();                         // acquire
    }
    __syncthreads();

    // ================= Part B: aggregate row i (R6-proven structure) =================
    const int grp = tid >> 4;   // 16 groups of 16 lanes
    const int gl  = tid & 15;
    const int d0  = gl * 4;
    const float attb  = att_b[0];
    const float Bi    = 1.f - x2i;
    const float coefi = fmaxf(Bi, MINV);         // = 2/lambda_i

    float4 vacc = make_float4(0.f, 0.f, 0.f, 0.f);
    float  s0   = 0.f;

    for (int cb = 0; cb < cnt; cb += CH) {
        const int m = min(CH, cnt - cb);

        // ---- stage neighbor rows into LDS (coalesced) ----
        {
            const int il = tid >> 4;
#pragma unroll
            for (int p = 0; p < 4; ++p) {
                const int ii = il + p * 16;
                if (ii < m) {
                    const int j = slist[cb + ii];
                    const float4 hv = *reinterpret_cast<const float4*>(H + j * DIM + d0);
                    float* dst = &Hl[ii][d0];
                    dst[0] = hv.x; dst[1] = hv.y; dst[2] = hv.z; dst[3] = hv.w;
                }
            }
        }
        __syncthreads();

        // ---- one pair per thread: dot + transcendentals ----
        if (tid < m) {
            const int j = slist[cb + tid];
            float dot = 0.f;
            const float* hr = Hl[tid];
#pragma unroll
            for (int d = 0; d < DIM; d += 2) {
                const float2 h2 = *reinterpret_cast<const float2*>(&hr[d]);
                dot = fmaf(shi[d + 0], h2.x, dot);
                dot = fmaf(shi[d + 1], h2.y, dot);
            }

            const float y2  = X2[j];
            const float A   = 1.f - 2.f * dot + y2;
            const float den = fmaxf(1.f - 2.f * dot + x2i * y2, MINV);
            const float q   = fmaxf(A * A * x2i - 2.f * A * Bi * dot + Bi * Bi * y2, 0.f);
            const float sn  = fmaxf(sqrtf(q) / den, MINV);
            const float ratio = artanh_f(sn) / sn;

            const float sig = 1.f / (1.f + expf(-(Li + R[j] + attb)));
            const float f   = sig * coefi * ratio / den;   // adj value is exactly 1.0

            f_arr[tid] = f;
            s0 += f * A;
        }
        __syncthreads();

        // ---- accumulate vacc from LDS (f broadcast per group) ----
        for (int il = grp; il < m; il += 16) {
            const float fv = f_arr[il];
            const float* hr = &Hl[il][d0];
            vacc.x = fmaf(fv, hr[0], vacc.x);
            vacc.y = fmaf(fv, hr[1], vacc.y);
            vacc.z = fmaf(fv, hr[2], vacc.z);
            vacc.w = fmaf(fv, hr[3], vacc.w);
        }
        __syncthreads();
    }

    // reduce vacc across the 4 groups of each wave
    vacc.x += __shfl_xor(vacc.x, 16, 64); vacc.x += __shfl_xor(vacc.x, 32, 64);
    vacc.y += __shfl_xor(vacc.y, 16, 64); vacc.y += __shfl_xor(vacc.y, 32, 64);
    vacc.z += __shfl_xor(vacc.z, 16, 64); vacc.z += __shfl_xor(vacc.z, 32, 64);
    vacc.w += __shfl_xor(vacc.w, 16, 64); vacc.w += __shfl_xor(vacc.w, 32, 64);
    s0 = waveReduceSum(s0);

    if (ln < 16) {
        svred[wv][ln * 4 + 0] = vacc.x;
        svred[wv][ln * 4 + 1] = vacc.y;
        svred[wv][ln * 4 + 2] = vacc.z;
        svred[wv][ln * 4 + 3] = vacc.w;
    }
    if (ln == 0) s0red[wv] = s0;
    __syncthreads();

    if (tid < DIM) {
        const float svec = svred[0][tid] + svred[1][tid] + svred[2][tid] + svred[3][tid];
        const float s0t  = s0red[0] + s0red[1] + s0red[2] + s0red[3];
        const float hd   = shi[tid];
        const float sup  = -s0t * hd + Bi * svec;          // support tangent vector

        // FAITHFUL: out = expmap(u=h, p=support)
        const float s2     = waveReduceSum(sup * sup);
        const float coef_s = fmaxf(1.f - s2, MINV);
        const float un     = fmaxf(sqrtf(x2i), MINV);      // ||h||
        const float tt     = tanhf(un / coef_s);
        const float sec    = tt * hd / un;

        float y2s = sec * sec, xy = sup * sec;
        waveReduceSum2(y2s, xy);
        const float num = (1.f + 2.f * xy + y2s) * sup + (1.f - s2) * sec;
        const float den = fmaxf(1.f + 2.f * xy + s2 * y2s, MINV);
        const float od  = num / den;

        // HypAct: expmap0(relu(logmap0(od)))
        const float on   = fmaxf(sqrtf(waveReduceSum(od * od)), MINV);
        const float tanv = artanh_f(on) / on * od;
        const float tv   = fmaxf(tanv, 0.f);
        const float tn   = fmaxf(sqrtf(waveReduceSum(tv * tv)), MINV);
        const float fin  = tanhf(tn) / tn * tv;

        out[i * DIM + tid] = fin;    // float32 output
    }
}

extern "C" void kernel_launch(void* const* d_in, const int* in_sizes, int n_in,
                              void* d_out, int out_size, void* d_ws, size_t ws_size,
                              hipStream_t stream) {
    const float* x      = (const float*)d_in[0];
    const float* adj    = (const float*)d_in[1];
    const float* weight = (const float*)d_in[2];
    const float* bias   = (const float*)d_in[3];
    const float* att_w  = (const float*)d_in[4];
    const float* att_b  = (const float*)d_in[5];

    float* ws = (float*)d_ws;
    float*    H   = ws;                       // 1024*64
    float*    X2  = ws + NODES * DIM;         // 1024
    float*    Lb  = X2 + NODES;               // 1024
    float*    Rb  = Lb + NODES;               // 1024
    unsigned* bar = (unsigned*)(Rb + NODES);  // 1 counter

    hipMemsetAsync(bar, 0, sizeof(unsigned), stream);   // capturable memset node
    fused_kernel<<<GRID, 256, 0, stream>>>(x, adj, weight, bias, att_w, att_b,
                                           H, X2, Lb, Rb, bar, (float*)d_out);
}

// Round 10
// 34.844 us; speedup vs baseline: 3.0790x; 3.0790x over previous
//
#include <hip/hip_runtime.h>
#include <hip/hip_bf16.h>

#define NODES 1024
#define DIM   64
#define MINV  1e-15f
#define EPSV  1e-7f
#define WPAD  66
#define HPAD  66
#define CH    64

// matches reference: clip to [-1+1e-7, 1-1e-7], 0.5*(log1p(y)-log1p(-y))
__device__ __forceinline__ float artanh_f(float y) {
    y = fminf(fmaxf(y, -1.f + EPSV), 1.f - EPSV);
    return 0.5f * (log1pf(y) - log1pf(-y));
}

__device__ __forceinline__ float waveReduceSum(float v) {
#pragma unroll
    for (int m = 1; m < 64; m <<= 1) v += __shfl_xor(v, m, 64);
    return v;
}

// two independent reductions with interleaved shuffles (halves dependent latency)
__device__ __forceinline__ void waveReduceSum2(float& a, float& b) {
#pragma unroll
    for (int m = 1; m < 64; m <<= 1) {
        const float ta = __shfl_xor(a, m, 64);
        const float tb = __shfl_xor(b, m, 64);
        a += ta; b += tb;
    }
}

// ---------------- Kernel 1: per-node prep (4 rows/block, W staged in LDS) ----------------
__global__ __launch_bounds__(256) void prep_kernel(
    const float* __restrict__ x,
    const float* __restrict__ weight,
    const float* __restrict__ bias,
    const float* __restrict__ att_w,
    float* __restrict__ H, float* __restrict__ X2,
    float* __restrict__ L, float* __restrict__ R)
{
    __shared__ float sx[4][DIM];
    __shared__ float Wl[DIM][WPAD];
    const int tid = threadIdx.x;
    const int wv  = tid >> 6;
    const int t   = tid & 63;
    const int i   = blockIdx.x * 4 + wv;

    // coalesced W fill: 4096 floats by 256 threads x float4
#pragma unroll
    for (int p = 0; p < 4; ++p) {
        const int k = p * 1024 + tid * 4;
        const float4 w4 = *reinterpret_cast<const float4*>(weight + k);
        const int r = k >> 6, c = k & 63;
        Wl[r][c + 0] = w4.x; Wl[r][c + 1] = w4.y;
        Wl[r][c + 2] = w4.z; Wl[r][c + 3] = w4.w;
    }

    const float xd = x[i * DIM + t];
    sx[wv][t] = xd;
    __syncthreads();

    const float xn = fmaxf(sqrtf(waveReduceSum(xd * xd)), MINV);

    float mx = 0.f;
    const float* sxr = sx[wv];
#pragma unroll
    for (int d = 0; d < DIM; d += 2) {
        const float2 w2 = *reinterpret_cast<const float2*>(&Wl[t][d]);
        mx = fmaf(sxr[d + 0], w2.x, mx);
        mx = fmaf(sxr[d + 1], w2.y, mx);
    }

    const float mxn = fmaxf(sqrtf(waveReduceSum(mx * mx)), MINV);
    const float res = tanhf(mxn / xn * artanh_f(xn)) * mx / mxn;   // mobius_matvec (c=1)

    const float bd = bias[t];
    const float bn = fmaxf(sqrtf(waveReduceSum(bd * bd)), MINV);
    const float hb = tanhf(bn) * bd / bn;                          // expmap0(bias)

    const float y2  = waveReduceSum(hb * hb);
    const float x2r = waveReduceSum(res * res);
    const float xy  = waveReduceSum(res * hb);
    const float num = (1.f + 2.f * xy + y2) * res + (1.f - x2r) * hb;
    const float den = fmaxf(1.f + 2.f * xy + x2r * y2, MINV);
    const float h   = num / den;                                   // mobius_add

    const float x2 = waveReduceSum(h * h);
    H[i * DIM + t] = h;

    const float n  = fmaxf(sqrtf(x2), MINV);
    const float ht = artanh_f(n) / n * h;                          // logmap0
    const float Li = waveReduceSum(ht * att_w[t]);
    const float Ri = waveReduceSum(ht * att_w[DIM + t]);

    if (t == 0) { X2[i] = x2; L[i] = Li; R[i] = Ri; }
}

// ---------------- Kernel 2: sparse aggregation (R6-proven), idempotent ----------------
__global__ __launch_bounds__(256) void agg_kernel(
    const float* __restrict__ H, const float* __restrict__ X2,
    const float* __restrict__ L, const float* __restrict__ R,
    const float* __restrict__ adj,
    const float* __restrict__ att_b,
    float* __restrict__ out)
{
    __shared__ float shi[DIM];
    __shared__ float Hl[CH][HPAD];
    __shared__ float f_arr[CH];
    __shared__ int   slist[NODES];
    __shared__ int   wbase[4];
    __shared__ float svred[4][DIM];
    __shared__ float s0red[4];

    const int i   = blockIdx.x;
    const int tid = threadIdx.x;
    const int wv  = tid >> 6;
    const int ln  = tid & 63;
    const int grp = tid >> 4;
    const int gl  = tid & 15;
    const int d0  = gl * 4;

    if (tid < DIM) shi[tid] = H[i * DIM + tid];

    // ---- deterministic compaction of the adj row ----
    const float4 a4 = *reinterpret_cast<const float4*>(adj + i * NODES + tid * 4);
    const int c0 = (a4.x != 0.f), c1 = (a4.y != 0.f), c2 = (a4.z != 0.f), c3 = (a4.w != 0.f);
    const int cntv = c0 + c1 + c2 + c3;

    int pfx = cntv;
#pragma unroll
    for (int d = 1; d < 64; d <<= 1) {
        const int tsh = __shfl_up(pfx, d, 64);
        if (ln >= d) pfx += tsh;
    }
    if (ln == 63) wbase[wv] = pfx;
    __syncthreads();

    int base = 0;
#pragma unroll
    for (int w = 0; w < 4; ++w) if (w < wv) base += wbase[w];
    int pos = base + pfx - cntv;
    const int j0 = tid * 4;
    if (c0) slist[pos++] = j0 + 0;
    if (c1) slist[pos++] = j0 + 1;
    if (c2) slist[pos++] = j0 + 2;
    if (c3) slist[pos++] = j0 + 3;
    __syncthreads();
    const int cnt = wbase[0] + wbase[1] + wbase[2] + wbase[3];

    const float x2i   = X2[i];
    const float Li    = L[i];
    const float Bi    = 1.f - x2i;
    const float coefi = fmaxf(Bi, MINV);
    const float attb  = att_b[0];

    float4 vacc = make_float4(0.f, 0.f, 0.f, 0.f);
    float  s0   = 0.f;

    for (int cb = 0; cb < cnt; cb += CH) {
        const int m = min(CH, cnt - cb);

        // ---- stage neighbor rows into LDS (coalesced) ----
        {
            const int il = tid >> 4;
#pragma unroll
            for (int p = 0; p < 4; ++p) {
                const int ii = il + p * 16;
                if (ii < m) {
                    const int j = slist[cb + ii];
                    const float4 hv = *reinterpret_cast<const float4*>(H + j * DIM + d0);
                    float* dst = &Hl[ii][d0];
                    dst[0] = hv.x; dst[1] = hv.y; dst[2] = hv.z; dst[3] = hv.w;
                }
            }
        }
        __syncthreads();

        // ---- one pair per thread: dot + transcendentals ----
        if (tid < m) {
            const int j = slist[cb + tid];
            float dot = 0.f;
            const float* hr = Hl[tid];
#pragma unroll
            for (int d = 0; d < DIM; d += 2) {
                const float2 h2 = *reinterpret_cast<const float2*>(&hr[d]);
                dot = fmaf(shi[d + 0], h2.x, dot);
                dot = fmaf(shi[d + 1], h2.y, dot);
            }

            const float y2  = X2[j];
            const float A   = 1.f - 2.f * dot + y2;
            const float den = fmaxf(1.f - 2.f * dot + x2i * y2, MINV);
            const float q   = fmaxf(A * A * x2i - 2.f * A * Bi * dot + Bi * Bi * y2, 0.f);
            const float sn  = fmaxf(sqrtf(q) / den, MINV);
            const float ratio = artanh_f(sn) / sn;

            const float sig = 1.f / (1.f + expf(-(Li + R[j] + attb)));
            const float f   = sig * coefi * ratio / den;   // adj value is exactly 1.0

            f_arr[tid] = f;
            s0 += f * A;
        }
        __syncthreads();

        // ---- accumulate vacc from LDS (f broadcast per group) ----
        for (int il = grp; il < m; il += 16) {
            const float fv = f_arr[il];
            const float* hr = &Hl[il][d0];
            vacc.x = fmaf(fv, hr[0], vacc.x);
            vacc.y = fmaf(fv, hr[1], vacc.y);
            vacc.z = fmaf(fv, hr[2], vacc.z);
            vacc.w = fmaf(fv, hr[3], vacc.w);
        }
        __syncthreads();
    }

    // reduce vacc across the 4 groups of each wave
    vacc.x += __shfl_xor(vacc.x, 16, 64); vacc.x += __shfl_xor(vacc.x, 32, 64);
    vacc.y += __shfl_xor(vacc.y, 16, 64); vacc.y += __shfl_xor(vacc.y, 32, 64);
    vacc.z += __shfl_xor(vacc.z, 16, 64); vacc.z += __shfl_xor(vacc.z, 32, 64);
    vacc.w += __shfl_xor(vacc.w, 16, 64); vacc.w += __shfl_xor(vacc.w, 32, 64);
    s0 = waveReduceSum(s0);

    if (ln < 16) {
        svred[wv][ln * 4 + 0] = vacc.x;
        svred[wv][ln * 4 + 1] = vacc.y;
        svred[wv][ln * 4 + 2] = vacc.z;
        svred[wv][ln * 4 + 3] = vacc.w;
    }
    if (ln == 0) s0red[wv] = s0;
    __syncthreads();

    if (tid < DIM) {
        const float svec = svred[0][tid] + svred[1][tid] + svred[2][tid] + svred[3][tid];
        const float s0t  = s0red[0] + s0red[1] + s0red[2] + s0red[3];
        const float hd   = shi[tid];
        const float sup  = -s0t * hd + Bi * svec;          // support tangent vector

        // FAITHFUL: out = expmap(u=h, p=support)
        const float s2     = waveReduceSum(sup * sup);
        const float coef_s = fmaxf(1.f - s2, MINV);
        const float un     = fmaxf(sqrtf(x2i), MINV);      // ||h||
        const float tt     = tanhf(un / coef_s);
        const float sec    = tt * hd / un;

        float y2s = sec * sec, xy = sup * sec;
        waveReduceSum2(y2s, xy);
        const float num = (1.f + 2.f * xy + y2s) * sup + (1.f - s2) * sec;
        const float den = fmaxf(1.f + 2.f * xy + s2 * y2s, MINV);
        const float od  = num / den;

        // HypAct: expmap0(relu(logmap0(od)))
        const float on   = fmaxf(sqrtf(waveReduceSum(od * od)), MINV);
        const float tanv = artanh_f(on) / on * od;
        const float tv   = fmaxf(tanv, 0.f);
        const float tn   = fmaxf(sqrtf(waveReduceSum(tv * tv)), MINV);
        const float fin  = tanhf(tn) / tn * tv;

        out[i * DIM + tid] = fin;    // float32 output
    }
}

extern "C" void kernel_launch(void* const* d_in, const int* in_sizes, int n_in,
                              void* d_out, int out_size, void* d_ws, size_t ws_size,
                              hipStream_t stream) {
    const float* x      = (const float*)d_in[0];
    const float* adj    = (const float*)d_in[1];
    const float* weight = (const float*)d_in[2];
    const float* bias   = (const float*)d_in[3];
    const float* att_w  = (const float*)d_in[4];
    const float* att_b  = (const float*)d_in[5];

    float* ws = (float*)d_ws;
    float* H  = ws;                       // 1024*64
    float* X2 = ws + NODES * DIM;         // 1024
    float* Lb = X2 + NODES;               // 1024
    float* Rb = Lb + NODES;               // 1024

    prep_kernel<<<NODES / 4, 256, 0, stream>>>(x, weight, bias, att_w, H, X2, Lb, Rb);
    // DIAGNOSTIC ROUND: agg launched 3x (idempotent, bit-identical output).
    // agg_time = (total_R10 - total_R6) / 2;  envelope+prep = total_R6 - agg_time.
    agg_kernel<<<NODES, 256, 0, stream>>>(H, X2, Lb, Rb, adj, att_b, (float*)d_out);
    agg_kernel<<<NODES, 256, 0, stream>>>(H, X2, Lb, Rb, adj, att_b, (float*)d_out);
    agg_kernel<<<NODES, 256, 0, stream>>>(H, X2, Lb, Rb, adj, att_b, (float*)d_out);
}

// Round 11
// 20.858 us; speedup vs baseline: 5.1437x; 1.6706x over previous
//
#include <hip/hip_runtime.h>
#include <hip/hip_bf16.h>

#define NODES 1024
#define DIM   64
#define MINV  1e-15f
#define EPSV  1e-7f
#define WPAD  66

// matches reference: clip to [-1+1e-7, 1-1e-7], 0.5*(log1p(y)-log1p(-y))
__device__ __forceinline__ float artanh_f(float y) {
    y = fminf(fmaxf(y, -1.f + EPSV), 1.f - EPSV);
    return 0.5f * (log1pf(y) - log1pf(-y));
}

__device__ __forceinline__ float waveReduceSum(float v) {
#pragma unroll
    for (int m = 1; m < 64; m <<= 1) v += __shfl_xor(v, m, 64);
    return v;
}

// two independent reductions with interleaved shuffles (halves dependent latency)
__device__ __forceinline__ void waveReduceSum2(float& a, float& b) {
#pragma unroll
    for (int m = 1; m < 64; m <<= 1) {
        const float ta = __shfl_xor(a, m, 64);
        const float tb = __shfl_xor(b, m, 64);
        a += ta; b += tb;
    }
}

// ---------------- Kernel 1: per-node prep (R6-proven, unchanged) ----------------
__global__ __launch_bounds__(256) void prep_kernel(
    const float* __restrict__ x,
    const float* __restrict__ weight,
    const float* __restrict__ bias,
    const float* __restrict__ att_w,
    float* __restrict__ H, float* __restrict__ X2,
    float* __restrict__ L, float* __restrict__ R)
{
    __shared__ float sx[4][DIM];
    __shared__ float Wl[DIM][WPAD];
    const int tid = threadIdx.x;
    const int wv  = tid >> 6;
    const int t   = tid & 63;
    const int i   = blockIdx.x * 4 + wv;

    // coalesced W fill: 4096 floats by 256 threads x float4
#pragma unroll
    for (int p = 0; p < 4; ++p) {
        const int k = p * 1024 + tid * 4;
        const float4 w4 = *reinterpret_cast<const float4*>(weight + k);
        const int r = k >> 6, c = k & 63;
        Wl[r][c + 0] = w4.x; Wl[r][c + 1] = w4.y;
        Wl[r][c + 2] = w4.z; Wl[r][c + 3] = w4.w;
    }

    const float xd = x[i * DIM + t];
    sx[wv][t] = xd;
    __syncthreads();

    const float xn = fmaxf(sqrtf(waveReduceSum(xd * xd)), MINV);

    float mx = 0.f;
    const float* sxr = sx[wv];
#pragma unroll
    for (int d = 0; d < DIM; d += 2) {
        const float2 w2 = *reinterpret_cast<const float2*>(&Wl[t][d]);
        mx = fmaf(sxr[d + 0], w2.x, mx);
        mx = fmaf(sxr[d + 1], w2.y, mx);
    }

    const float mxn = fmaxf(sqrtf(waveReduceSum(mx * mx)), MINV);
    const float res = tanhf(mxn / xn * artanh_f(xn)) * mx / mxn;   // mobius_matvec (c=1)

    const float bd = bias[t];
    const float bn = fmaxf(sqrtf(waveReduceSum(bd * bd)), MINV);
    const float hb = tanhf(bn) * bd / bn;                          // expmap0(bias)

    const float y2  = waveReduceSum(hb * hb);
    const float x2r = waveReduceSum(res * res);
    const float xy  = waveReduceSum(res * hb);
    const float num = (1.f + 2.f * xy + y2) * res + (1.f - x2r) * hb;
    const float den = fmaxf(1.f + 2.f * xy + x2r * y2, MINV);
    const float h   = num / den;                                   // mobius_add

    const float x2 = waveReduceSum(h * h);
    H[i * DIM + t] = h;

    const float n  = fmaxf(sqrtf(x2), MINV);
    const float ht = artanh_f(n) / n * h;                          // logmap0
    const float Li = waveReduceSum(ht * att_w[t]);
    const float Ri = waveReduceSum(ht * att_w[DIM + t]);

    if (t == 0) { X2[i] = x2; L[i] = Li; R[i] = Ri; }
}

// ---------------- Kernel 2: agg-v3 — all-wave pair phase, no LDS staging ----------------
// support_i = -(sum_j f_ij*A_ij) * h_i + B_i * (sum_j f_ij * h_j)
// f_ij = sigmoid(L_i+R_j+b) * coefi * artanh(sn)/sn / den_ij   (adj nonzeros are exactly 1.0)
// EPILOGUE: faithful swapped call expmap(u=h, p=support)
__global__ __launch_bounds__(256) void agg_kernel(
    const float* __restrict__ H, const float* __restrict__ X2,
    const float* __restrict__ L, const float* __restrict__ R,
    const float* __restrict__ adj,
    const float* __restrict__ att_b,
    float* __restrict__ out)
{
    __shared__ float shi[DIM];
    __shared__ float f_arr[NODES];
    __shared__ int   slist[NODES];
    __shared__ int   wbase[4];
    __shared__ float svred[4][DIM];
    __shared__ float s0red[4];

    const int i   = blockIdx.x;
    const int tid = threadIdx.x;
    const int wv  = tid >> 6;
    const int ln  = tid & 63;
    const int grp = tid >> 4;
    const int gl  = tid & 15;
    const int d0  = gl * 4;

    if (tid < DIM) shi[tid] = H[i * DIM + tid];

    // ---- deterministic compaction of the adj row (R6-proven) ----
    const float4 a4 = *reinterpret_cast<const float4*>(adj + i * NODES + tid * 4);
    const int c0 = (a4.x != 0.f), c1 = (a4.y != 0.f), c2 = (a4.z != 0.f), c3 = (a4.w != 0.f);
    const int cntv = c0 + c1 + c2 + c3;

    int pfx = cntv;
#pragma unroll
    for (int d = 1; d < 64; d <<= 1) {
        const int tsh = __shfl_up(pfx, d, 64);
        if (ln >= d) pfx += tsh;
    }
    if (ln == 63) wbase[wv] = pfx;
    __syncthreads();

    int base = 0;
#pragma unroll
    for (int w = 0; w < 4; ++w) if (w < wv) base += wbase[w];
    int pos = base + pfx - cntv;
    const int j0 = tid * 4;
    if (c0) slist[pos++] = j0 + 0;
    if (c1) slist[pos++] = j0 + 1;
    if (c2) slist[pos++] = j0 + 2;
    if (c3) slist[pos++] = j0 + 3;
    __syncthreads();
    const int cnt = wbase[0] + wbase[1] + wbase[2] + wbase[3];

    const float x2i   = X2[i];
    const float Li    = L[i];
    const float Bi    = 1.f - x2i;
    const float coefi = fmaxf(Bi, MINV);
    const float attb  = att_b[0];

    // ---- phase 2: pairs spread across ALL 4 waves (k = ln*4 + wv), H rows direct from L2 ----
    float s0 = 0.f;
    for (int kb = 0; kb < cnt; kb += 256) {
        const int k = kb + ln * 4 + wv;
        if (k < cnt) {
            const int j = slist[k];
            float dot = 0.f;
            const float* hj = H + j * DIM;
#pragma unroll
            for (int d = 0; d < DIM; d += 4) {
                const float4 h4 = *reinterpret_cast<const float4*>(hj + d);
                dot = fmaf(h4.x, shi[d + 0], dot);
                dot = fmaf(h4.y, shi[d + 1], dot);
                dot = fmaf(h4.z, shi[d + 2], dot);
                dot = fmaf(h4.w, shi[d + 3], dot);
            }

            const float y2  = X2[j];
            const float A   = 1.f - 2.f * dot + y2;
            const float den = fmaxf(1.f - 2.f * dot + x2i * y2, MINV);
            const float q   = fmaxf(A * A * x2i - 2.f * A * Bi * dot + Bi * Bi * y2, 0.f);
            const float sn  = fmaxf(sqrtf(q) / den, MINV);
            const float ratio = artanh_f(sn) / sn;

            const float sig = 1.f / (1.f + expf(-(Li + R[j] + attb)));
            const float f   = sig * coefi * ratio / den;   // adj value is exactly 1.0

            f_arr[k] = f;
            s0 += f * A;
        }
    }
    __syncthreads();

    // ---- phase 3: dim-parallel accumulation, H re-read from L2 (lines hot), ascending j ----
    float4 vacc = make_float4(0.f, 0.f, 0.f, 0.f);
    for (int il = grp; il < cnt; il += 16) {
        const int j   = slist[il];                 // uniform within group
        const float f = f_arr[il];                 // broadcast
        const float4 hv = *reinterpret_cast<const float4*>(H + j * DIM + d0);
        vacc.x = fmaf(f, hv.x, vacc.x);
        vacc.y = fmaf(f, hv.y, vacc.y);
        vacc.z = fmaf(f, hv.z, vacc.z);
        vacc.w = fmaf(f, hv.w, vacc.w);
    }

    // reduce vacc across the 4 groups of each wave; s0 across waves
    vacc.x += __shfl_xor(vacc.x, 16, 64); vacc.x += __shfl_xor(vacc.x, 32, 64);
    vacc.y += __shfl_xor(vacc.y, 16, 64); vacc.y += __shfl_xor(vacc.y, 32, 64);
    vacc.z += __shfl_xor(vacc.z, 16, 64); vacc.z += __shfl_xor(vacc.z, 32, 64);
    vacc.w += __shfl_xor(vacc.w, 16, 64); vacc.w += __shfl_xor(vacc.w, 32, 64);
    s0 = waveReduceSum(s0);

    if (ln < 16) {
        svred[wv][ln * 4 + 0] = vacc.x;
        svred[wv][ln * 4 + 1] = vacc.y;
        svred[wv][ln * 4 + 2] = vacc.z;
        svred[wv][ln * 4 + 3] = vacc.w;
    }
    if (ln == 0) s0red[wv] = s0;
    __syncthreads();

    if (tid < DIM) {
        const float svec = svred[0][tid] + svred[1][tid] + svred[2][tid] + svred[3][tid];
        const float s0t  = s0red[0] + s0red[1] + s0red[2] + s0red[3];
        const float hd   = shi[tid];
        const float sup  = -s0t * hd + Bi * svec;          // support tangent vector

        // FAITHFUL: out = expmap(u=h, p=support)
        const float s2     = waveReduceSum(sup * sup);
        const float coef_s = fmaxf(1.f - s2, MINV);
        const float un     = fmaxf(sqrtf(x2i), MINV);      // ||h||
        const float tt     = tanhf(un / coef_s);
        const float sec    = tt * hd / un;

        float y2s = sec * sec, xy = sup * sec;
        waveReduceSum2(y2s, xy);
        const float num = (1.f + 2.f * xy + y2s) * sup + (1.f - s2) * sec;
        const float den = fmaxf(1.f + 2.f * xy + s2 * y2s, MINV);
        const float od  = num / den;

        // HypAct: expmap0(relu(logmap0(od)))
        const float on   = fmaxf(sqrtf(waveReduceSum(od * od)), MINV);
        const float tanv = artanh_f(on) / on * od;
        const float tv   = fmaxf(tanv, 0.f);
        const float tn   = fmaxf(sqrtf(waveReduceSum(tv * tv)), MINV);
        const float fin  = tanhf(tn) / tn * tv;

        out[i * DIM + tid] = fin;    // float32 output
    }
}

extern "C" void kernel_launch(void* const* d_in, const int* in_sizes, int n_in,
                              void* d_out, int out_size, void* d_ws, size_t ws_size,
                              hipStream_t stream) {
    const float* x      = (const float*)d_in[0];
    const float* adj    = (const float*)d_in[1];
    const float* weight = (const float*)d_in[2];
    const float* bias   = (const float*)d_in[3];
    const float* att_w  = (const float*)d_in[4];
    const float* att_b  = (const float*)d_in[5];

    float* ws = (float*)d_ws;
    float* H  = ws;                       // 1024*64
    float* X2 = ws + NODES * DIM;         // 1024
    float* Lb = X2 + NODES;               // 1024
    float* Rb = Lb + NODES;               // 1024

    prep_kernel<<<NODES / 4, 256, 0, stream>>>(x, weight, bias, att_w, H, X2, Lb, Rb);
    agg_kernel<<<NODES, 256, 0, stream>>>(H, X2, Lb, Rb, adj, att_b, (float*)d_out);
}

// Round 12
// 19.190 us; speedup vs baseline: 5.5907x; 1.0869x over previous
//
#include <hip/hip_runtime.h>
#include <hip/hip_bf16.h>

#define NODES 1024
#define DIM   64
#define MINV  1e-15f
#define EPSV  1e-7f
#define HPAD  66
#define CH    64

// matches reference: clip to [-1+1e-7, 1-1e-7], 0.5*(log1p(y)-log1p(-y))
__device__ __forceinline__ float artanh_f(float y) {
    y = fminf(fmaxf(y, -1.f + EPSV), 1.f - EPSV);
    return 0.5f * (log1pf(y) - log1pf(-y));
}

__device__ __forceinline__ float waveReduceSum(float v) {
#pragma unroll
    for (int m = 1; m < 64; m <<= 1) v += __shfl_xor(v, m, 64);
    return v;
}
// independent reductions, interleaved shuffles: same per-sum order, lower latency
__device__ __forceinline__ void waveReduceSum2(float& a, float& b) {
#pragma unroll
    for (int m = 1; m < 64; m <<= 1) {
        const float ta = __shfl_xor(a, m, 64);
        const float tb = __shfl_xor(b, m, 64);
        a += ta; b += tb;
    }
}
__device__ __forceinline__ void waveReduceSum3(float& a, float& b, float& c) {
#pragma unroll
    for (int m = 1; m < 64; m <<= 1) {
        const float ta = __shfl_xor(a, m, 64);
        const float tb = __shfl_xor(b, m, 64);
        const float tc = __shfl_xor(c, m, 64);
        a += ta; b += tb; c += tc;
    }
}

// ---------------- Kernel 1: prep-v3 — 4 rows/block, W direct from global (L1-hot, 16KB) ----------------
__global__ __launch_bounds__(256) void prep_kernel(
    const float* __restrict__ x,
    const float* __restrict__ weight,
    const float* __restrict__ bias,
    const float* __restrict__ att_w,
    float* __restrict__ H, float* __restrict__ X2,
    float* __restrict__ L, float* __restrict__ R)
{
    __shared__ float sx[4][DIM];
    const int tid = threadIdx.x;
    const int wv  = tid >> 6;
    const int t   = tid & 63;
    const int i   = blockIdx.x * 4 + wv;

    const float xd = x[i * DIM + t];
    sx[wv][t] = xd;            // wave-local; same-wave RAW ordered by lgkmcnt (no barrier needed)

    // mx[t] = sum_d x[d] * W[t][d]  (einsum 'bnd,ed->bne'); W row from global — L1-resident
    float mx = 0.f;
    const float* wrow = weight + t * DIM;
    const float* sxr  = sx[wv];
#pragma unroll
    for (int d = 0; d < DIM; d += 4) {
        const float4 w4 = *reinterpret_cast<const float4*>(wrow + d);
        mx = fmaf(sxr[d + 0], w4.x, mx);
        mx = fmaf(sxr[d + 1], w4.y, mx);
        mx = fmaf(sxr[d + 2], w4.z, mx);
        mx = fmaf(sxr[d + 3], w4.w, mx);
    }

    const float bd = bias[t];
    float xn2 = xd * xd, mxn2 = mx * mx, bn2 = bd * bd;
    waveReduceSum3(xn2, mxn2, bn2);
    const float xn  = fmaxf(sqrtf(xn2), MINV);
    const float mxn = fmaxf(sqrtf(mxn2), MINV);
    const float res = tanhf(mxn / xn * artanh_f(xn)) * mx / mxn;   // mobius_matvec (c=1)
    const float bn  = fmaxf(sqrtf(bn2), MINV);
    const float hb  = tanhf(bn) * bd / bn;                         // expmap0(bias)

    float y2 = hb * hb, x2r = res * res, xy = res * hb;
    waveReduceSum3(y2, x2r, xy);
    const float num = (1.f + 2.f * xy + y2) * res + (1.f - x2r) * hb;
    const float den = fmaxf(1.f + 2.f * xy + x2r * y2, MINV);
    const float h   = num / den;                                   // mobius_add -> h

    const float x2 = waveReduceSum(h * h);
    H[i * DIM + t] = h;

    const float n  = fmaxf(sqrtf(x2), MINV);
    const float ht = artanh_f(n) / n * h;                          // logmap0
    float Li = ht * att_w[t], Ri = ht * att_w[DIM + t];
    waveReduceSum2(Li, Ri);

    if (t == 0) { X2[i] = x2; L[i] = Li; R[i] = Ri; }
}

// ---------------- Kernel 2: sparse aggregation (R6-proven, byte-identical) ----------------
__global__ __launch_bounds__(256) void agg_kernel(
    const float* __restrict__ H, const float* __restrict__ X2,
    const float* __restrict__ L, const float* __restrict__ R,
    const float* __restrict__ adj,
    const float* __restrict__ att_b,
    float* __restrict__ out)
{
    __shared__ float shi[DIM];
    __shared__ float Hl[CH][HPAD];
    __shared__ float f_arr[CH];
    __shared__ int   slist[NODES];
    __shared__ int   wbase[4];
    __shared__ float svred[4][DIM];
    __shared__ float s0red[4];

    const int i   = blockIdx.x;
    const int tid = threadIdx.x;
    const int wv  = tid >> 6;
    const int ln  = tid & 63;
    const int grp = tid >> 4;
    const int gl  = tid & 15;
    const int d0  = gl * 4;

    if (tid < DIM) shi[tid] = H[i * DIM + tid];

    // ---- deterministic compaction of the adj row ----
    const float4 a4 = *reinterpret_cast<const float4*>(adj + i * NODES + tid * 4);
    const int c0 = (a4.x != 0.f), c1 = (a4.y != 0.f), c2 = (a4.z != 0.f), c3 = (a4.w != 0.f);
    const int cntv = c0 + c1 + c2 + c3;

    int pfx = cntv;
#pragma unroll
    for (int d = 1; d < 64; d <<= 1) {
        const int tsh = __shfl_up(pfx, d, 64);
        if (ln >= d) pfx += tsh;
    }
    if (ln == 63) wbase[wv] = pfx;
    __syncthreads();

    int base = 0;
#pragma unroll
    for (int w = 0; w < 4; ++w) if (w < wv) base += wbase[w];
    int pos = base + pfx - cntv;
    const int j0 = tid * 4;
    if (c0) slist[pos++] = j0 + 0;
    if (c1) slist[pos++] = j0 + 1;
    if (c2) slist[pos++] = j0 + 2;
    if (c3) slist[pos++] = j0 + 3;
    __syncthreads();
    const int cnt = wbase[0] + wbase[1] + wbase[2] + wbase[3];

    const float x2i   = X2[i];
    const float Li    = L[i];
    const float Bi    = 1.f - x2i;
    const float coefi = fmaxf(Bi, MINV);
    const float attb  = att_b[0];

    float4 vacc = make_float4(0.f, 0.f, 0.f, 0.f);
    float  s0   = 0.f;

    for (int cb = 0; cb < cnt; cb += CH) {
        const int m = min(CH, cnt - cb);

        // ---- stage neighbor rows into LDS (coalesced) ----
        {
            const int il = tid >> 4;
#pragma unroll
            for (int p = 0; p < 4; ++p) {
                const int ii = il + p * 16;
                if (ii < m) {
                    const int j = slist[cb + ii];
                    const float4 hv = *reinterpret_cast<const float4*>(H + j * DIM + d0);
                    float* dst = &Hl[ii][d0];
                    dst[0] = hv.x; dst[1] = hv.y; dst[2] = hv.z; dst[3] = hv.w;
                }
            }
        }
        __syncthreads();

        // ---- one pair per thread: dot + transcendentals ----
        if (tid < m) {
            const int j = slist[cb + tid];
            float dot = 0.f;
            const float* hr = Hl[tid];
#pragma unroll
            for (int d = 0; d < DIM; d += 2) {
                const float2 h2 = *reinterpret_cast<const float2*>(&hr[d]);
                dot = fmaf(shi[d + 0], h2.x, dot);
                dot = fmaf(shi[d + 1], h2.y, dot);
            }

            const float y2  = X2[j];
            const float A   = 1.f - 2.f * dot + y2;
            const float den = fmaxf(1.f - 2.f * dot + x2i * y2, MINV);
            const float q   = fmaxf(A * A * x2i - 2.f * A * Bi * dot + Bi * Bi * y2, 0.f);
            const float sn  = fmaxf(sqrtf(q) / den, MINV);
            const float ratio = artanh_f(sn) / sn;

            const float sig = 1.f / (1.f + expf(-(Li + R[j] + attb)));
            const float f   = sig * coefi * ratio / den;   // adj value is exactly 1.0

            f_arr[tid] = f;
            s0 += f * A;
        }
        __syncthreads();

        // ---- accumulate vacc from LDS (f broadcast per group) ----
        for (int il = grp; il < m; il += 16) {
            const float fv = f_arr[il];
            const float* hr = &Hl[il][d0];
            vacc.x = fmaf(fv, hr[0], vacc.x);
            vacc.y = fmaf(fv, hr[1], vacc.y);
            vacc.z = fmaf(fv, hr[2], vacc.z);
            vacc.w = fmaf(fv, hr[3], vacc.w);
        }
        __syncthreads();
    }

    // reduce vacc across the 4 groups of each wave
    vacc.x += __shfl_xor(vacc.x, 16, 64); vacc.x += __shfl_xor(vacc.x, 32, 64);
    vacc.y += __shfl_xor(vacc.y, 16, 64); vacc.y += __shfl_xor(vacc.y, 32, 64);
    vacc.z += __shfl_xor(vacc.z, 16, 64); vacc.z += __shfl_xor(vacc.z, 32, 64);
    vacc.w += __shfl_xor(vacc.w, 16, 64); vacc.w += __shfl_xor(vacc.w, 32, 64);
    s0 = waveReduceSum(s0);

    if (ln < 16) {
        svred[wv][ln * 4 + 0] = vacc.x;
        svred[wv][ln * 4 + 1] = vacc.y;
        svred[wv][ln * 4 + 2] = vacc.z;
        svred[wv][ln * 4 + 3] = vacc.w;
    }
    if (ln == 0) s0red[wv] = s0;
    __syncthreads();

    if (tid < DIM) {
        const float svec = svred[0][tid] + svred[1][tid] + svred[2][tid] + svred[3][tid];
        const float s0t  = s0red[0] + s0red[1] + s0red[2] + s0red[3];
        const float hd   = shi[tid];
        const float sup  = -s0t * hd + Bi * svec;          // support tangent vector

        // FAITHFUL: out = expmap(u=h, p=support)
        const float s2     = waveReduceSum(sup * sup);
        const float coef_s = fmaxf(1.f - s2, MINV);
        const float un     = fmaxf(sqrtf(x2i), MINV);      // ||h||
        const float tt     = tanhf(un / coef_s);
        const float sec    = tt * hd / un;

        float y2s = sec * sec, xy = sup * sec;
        waveReduceSum2(y2s, xy);
        const float num = (1.f + 2.f * xy + y2s) * sup + (1.f - s2) * sec;
        const float den = fmaxf(1.f + 2.f * xy + s2 * y2s, MINV);
        const float od  = num / den;

        // HypAct: expmap0(relu(logmap0(od)))
        const float on   = fmaxf(sqrtf(waveReduceSum(od * od)), MINV);
        const float tanv = artanh_f(on) / on * od;
        const float tv   = fmaxf(tanv, 0.f);
        const float tn   = fmaxf(sqrtf(waveReduceSum(tv * tv)), MINV);
        const float fin  = tanhf(tn) / tn * tv;

        out[i * DIM + tid] = fin;    // float32 output
    }
}

extern "C" void kernel_launch(void* const* d_in, const int* in_sizes, int n_in,
                              void* d_out, int out_size, void* d_ws, size_t ws_size,
                              hipStream_t stream) {
    const float* x      = (const float*)d_in[0];
    const float* adj    = (const float*)d_in[1];
    const float* weight = (const float*)d_in[2];
    const float* bias   = (const float*)d_in[3];
    const float* att_w  = (const float*)d_in[4];
    const float* att_b  = (const float*)d_in[5];

    float* ws = (float*)d_ws;
    float* H  = ws;                       // 1024*64
    float* X2 = ws + NODES * DIM;         // 1024
    float* Lb = X2 + NODES;               // 1024
    float* Rb = Lb + NODES;               // 1024

    prep_kernel<<<NODES / 4, 256, 0, stream>>>(x, weight, bias, att_w, H, X2, Lb, Rb);
    agg_kernel<<<NODES, 256, 0, stream>>>(H, X2, Lb, Rb, adj, att_b, (float*)d_out);
}